// Round 1
// baseline (331.975 us; speedup 1.0000x reference)
//
#include <hip/hip_runtime.h>
#include <hip/hip_bf16.h>

// Mamba block fwd, B=2 L=2048 DM=768 DI=1536 DS=16 DCONV=4 DTR=48
// Pipeline: rmsnorm(bf16) -> gemm1(in_proj) -> conv+silu -> gemm2(x_proj)
//           -> gemm3(dt_proj, softplus epi) -> chunked scan (3 passes, fused
//           C-reduce + D*xs + silu(z) gate) -> gemm4(out_proj, +x residual)
// GEMMs: bf16 MFMA 16x16x32, fp32 accum, 64x64 tile, 4 waves.

#define BB 2
#define LL 2048
#define DM 768
#define DI 1536
#define DS 16
#define DTR 48
#define NC 64
#define CL 32

typedef __attribute__((ext_vector_type(8))) __bf16 bf16x8;
typedef __attribute__((ext_vector_type(4))) float f32x4;

// ---------------- RMSNorm -> bf16 ----------------
__global__ __launch_bounds__(256) void rmsnorm_kernel(
    const float* __restrict__ x, const float* __restrict__ rmsw,
    __hip_bfloat16* __restrict__ xn) {
  const int row = blockIdx.x;
  const int tid = threadIdx.x;
  const float* xr = x + (size_t)row * DM;
  float v0 = xr[tid], v1 = xr[tid + 256], v2 = xr[tid + 512];
  float ss = v0 * v0 + v1 * v1 + v2 * v2;
  for (int off = 32; off; off >>= 1) ss += __shfl_down(ss, off);
  __shared__ float sred[4];
  __shared__ float sscale;
  if ((tid & 63) == 0) sred[tid >> 6] = ss;
  __syncthreads();
  if (tid == 0) {
    float s = sred[0] + sred[1] + sred[2] + sred[3];
    sscale = rsqrtf(s * (1.f / DM) + 1e-5f);
  }
  __syncthreads();
  float sc = sscale;
  __hip_bfloat16* o = xn + (size_t)row * DM;
  o[tid]       = __float2bfloat16(v0 * sc * rmsw[tid]);
  o[tid + 256] = __float2bfloat16(v1 * sc * rmsw[tid + 256]);
  o[tid + 512] = __float2bfloat16(v2 * sc * rmsw[tid + 512]);
}

// ---------------- fp32 -> bf16 converters ----------------
__global__ __launch_bounds__(256) void cvt_bf16(
    const float* __restrict__ in, __hip_bfloat16* __restrict__ o, int n) {
  int idx = blockIdx.x * 256 + threadIdx.x;
  if (idx < n) o[idx] = __float2bfloat16(in[idx]);
}

// dt_proj_w (1536,48) -> (1536,64) zero-padded bf16
__global__ __launch_bounds__(256) void cvt_dtw(
    const float* __restrict__ w, __hip_bfloat16* __restrict__ o) {
  int idx = blockIdx.x * 256 + threadIdx.x;  // 1536*64
  int n = idx >> 6, k = idx & 63;
  o[idx] = __float2bfloat16(k < DTR ? w[n * DTR + k] : 0.f);
}

// dBC delta part (4096,80 cols 0..47) -> (4096,64) zero-padded bf16
__global__ __launch_bounds__(256) void split_dbc(
    const float* __restrict__ dBC, __hip_bfloat16* __restrict__ din) {
  int idx = blockIdx.x * 256 + threadIdx.x;  // 4096*64
  int m = idx >> 6, k = idx & 63;
  float v = (k < DTR) ? dBC[(size_t)m * 80 + k] : 0.f;
  din[idx] = __float2bfloat16(v);
}

// ---------------- GEMM: C[M,N] = A[M,K] * B[N,K]^T (bf16 in, fp32 out) ------
// EPI 0: none. EPI 1: softplus(acc + bias[n]). EPI 2: acc + res[m,n].
template <int EPI>
__global__ __launch_bounds__(256) void gemm_bt(
    const unsigned short* __restrict__ A, const unsigned short* __restrict__ B,
    float* __restrict__ C, int M, int N, int K, const float* __restrict__ ep) {
  __shared__ unsigned short Al[64 * 40];
  __shared__ unsigned short Bl[64 * 40];
  const int tid = threadIdx.x;
  const int m0 = blockIdx.y << 6, n0 = blockIdx.x << 6;
  const int srow = tid >> 2, scg = tid & 3;
  const int wave = tid >> 6, lane = tid & 63;
  const int wm = wave >> 1, wn = wave & 1;
  const int lr = lane & 15, q = lane >> 4;
  f32x4 acc[2][2] = {};
  const size_t arow_off = (size_t)(m0 + srow) * K + scg * 8;
  const int brow = n0 + srow;
  const size_t brow_off = (size_t)brow * K + scg * 8;
  for (int k0 = 0; k0 < K; k0 += 32) {
    int4 av = *(const int4*)(A + arow_off + k0);
    int4 bv = make_int4(0, 0, 0, 0);
    if (brow < N) bv = *(const int4*)(B + brow_off + k0);
    __syncthreads();
    *(int4*)(Al + srow * 40 + scg * 8) = av;
    *(int4*)(Bl + srow * 40 + scg * 8) = bv;
    __syncthreads();
    bf16x8 af[2], bfr[2];
#pragma unroll
    for (int mi = 0; mi < 2; ++mi)
      af[mi] = *(const bf16x8*)(Al + (wm * 32 + mi * 16 + lr) * 40 + q * 8);
#pragma unroll
    for (int ni = 0; ni < 2; ++ni)
      bfr[ni] = *(const bf16x8*)(Bl + (wn * 32 + ni * 16 + lr) * 40 + q * 8);
#pragma unroll
    for (int mi = 0; mi < 2; ++mi)
#pragma unroll
      for (int ni = 0; ni < 2; ++ni)
        acc[mi][ni] = __builtin_amdgcn_mfma_f32_16x16x32_bf16(
            af[mi], bfr[ni], acc[mi][ni], 0, 0, 0);
  }
#pragma unroll
  for (int mi = 0; mi < 2; ++mi) {
#pragma unroll
    for (int ni = 0; ni < 2; ++ni) {
      int nn = n0 + wn * 32 + ni * 16 + lr;
      if (nn >= N) continue;
      int mbase = m0 + wm * 32 + mi * 16 + q * 4;
#pragma unroll
      for (int r = 0; r < 4; ++r) {
        float v = acc[mi][ni][r];
        size_t ci = (size_t)(mbase + r) * N + nn;
        if (EPI == 1) {
          v += ep[nn];
          v = fmaxf(v, 0.f) + log1pf(__expf(-fabsf(v)));
        } else if (EPI == 2) {
          v += ep[ci];
        }
        C[ci] = v;
      }
    }
  }
}

// ---------------- causal depthwise conv (k=4) + SiLU ----------------
__global__ __launch_bounds__(256) void conv_silu_kernel(
    const float* __restrict__ xz, const float* __restrict__ cw,
    const float* __restrict__ cb, float* __restrict__ xs,
    __hip_bfloat16* __restrict__ xsb) {
  int idx = blockIdx.x * 256 + threadIdx.x;  // BB*LL*DI
  int d = idx % DI;
  int bl = idx / DI;
  int l = bl & (LL - 1);
  float acc = cb[d];
#pragma unroll
  for (int j = 0; j < 4; ++j) {
    int ls = l - 3 + j;
    if (ls >= 0) acc += xz[(size_t)(bl - 3 + j) * (2 * DI) + d] * cw[d * 4 + j];
  }
  float s = acc * (1.f / (1.f + __expf(-acc)));
  xs[idx] = s;
  xsb[idx] = __float2bfloat16(s);
}

// ---------------- scan pass A: per-chunk carries ----------------
__global__ __launch_bounds__(256) void scan_passA(
    const float* __restrict__ delta, const float* __restrict__ xs,
    const float* __restrict__ dBC, const float* __restrict__ A_log,
    float* __restrict__ cA, float* __restrict__ cB) {
  __shared__ float Bs[CL * DS];
  const int bid = blockIdx.x;
  const int dg = bid % 6;
  const int chunk = (bid / 6) % NC;
  const int b = bid / (6 * NC);
  const int tid = threadIdx.x;
  const int d = dg * 256 + tid;
  const size_t bl0 = (size_t)b * LL + chunk * CL;
  for (int i = tid; i < CL * DS; i += 256) {
    int l = i >> 4, n = i & 15;
    Bs[i] = dBC[(bl0 + l) * 80 + DTR + n];
  }
  float Av[DS];
#pragma unroll
  for (int n = 0; n < DS; ++n) Av[n] = -__expf(A_log[d * DS + n]);
  float ap[DS], bc[DS];
#pragma unroll
  for (int n = 0; n < DS; ++n) { ap[n] = 1.f; bc[n] = 0.f; }
  __syncthreads();
  for (int t = 0; t < CL; ++t) {
    float dv = delta[(bl0 + t) * DI + d];
    float xv = xs[(bl0 + t) * DI + d];
    float dx = dv * xv;
#pragma unroll
    for (int n = 0; n < DS; ++n) {
      float a = __expf(dv * Av[n]) * 2.f - 1.f;
      bc[n] = a * bc[n] + dx * Bs[t * DS + n];
      ap[n] *= a;
    }
  }
  size_t base = ((size_t)(b * NC + chunk) * DS) * DI + d;
#pragma unroll
  for (int n = 0; n < DS; ++n) {
    cA[base + (size_t)n * DI] = ap[n];
    cB[base + (size_t)n * DI] = bc[n];
  }
}

// ---------------- scan pass B: scan over chunk aggregates ----------------
__global__ __launch_bounds__(256) void scan_passB(
    const float* __restrict__ cA, const float* __restrict__ cB,
    float* __restrict__ hinit) {
  int idx = blockIdx.x * 256 + threadIdx.x;  // BB*DS*DI
  int d = idx % DI;
  int n = (idx / DI) % DS;
  int b = idx / (DI * DS);
  float h = 0.f;
  for (int c = 0; c < NC; ++c) {
    size_t base = ((size_t)(b * NC + c) * DS + n) * DI + d;
    hinit[base] = h;
    h = cA[base] * h + cB[base];
  }
}

// ---------------- scan pass C: replay + C-reduce + D*xs + silu(z) gate -----
__global__ __launch_bounds__(256) void scan_passC(
    const float* __restrict__ delta, const float* __restrict__ xs,
    const float* __restrict__ dBC, const float* __restrict__ A_log,
    const float* __restrict__ Dv, const float* __restrict__ xz,
    const float* __restrict__ hinit, __hip_bfloat16* __restrict__ yg) {
  __shared__ float Bs[CL * DS];
  __shared__ float Cs[CL * DS];
  const int bid = blockIdx.x;
  const int dg = bid % 6;
  const int chunk = (bid / 6) % NC;
  const int b = bid / (6 * NC);
  const int tid = threadIdx.x;
  const int d = dg * 256 + tid;
  const size_t bl0 = (size_t)b * LL + chunk * CL;
  for (int i = tid; i < CL * DS; i += 256) {
    int l = i >> 4, n = i & 15;
    Bs[i] = dBC[(bl0 + l) * 80 + DTR + n];
    Cs[i] = dBC[(bl0 + l) * 80 + DTR + DS + n];
  }
  float Av[DS];
#pragma unroll
  for (int n = 0; n < DS; ++n) Av[n] = -__expf(A_log[d * DS + n]);
  float h[DS];
  size_t hbase = ((size_t)(b * NC + chunk) * DS) * DI + d;
#pragma unroll
  for (int n = 0; n < DS; ++n) h[n] = hinit[hbase + (size_t)n * DI];
  float Dd = Dv[d];
  __syncthreads();
  for (int t = 0; t < CL; ++t) {
    float dv = delta[(bl0 + t) * DI + d];
    float xv = xs[(bl0 + t) * DI + d];
    float zv = xz[(bl0 + t) * (2 * DI) + DI + d];
    float dx = dv * xv;
    float y = 0.f;
#pragma unroll
    for (int n = 0; n < DS; ++n) {
      float a = __expf(dv * Av[n]) * 2.f - 1.f;
      h[n] = a * h[n] + dx * Bs[t * DS + n];
      y += h[n] * Cs[t * DS + n];
    }
    y += Dd * xv;
    float g = zv / (1.f + __expf(-zv));
    yg[(bl0 + t) * DI + d] = __float2bfloat16(y * g);
  }
}

// ---------------- host launch ----------------
extern "C" void kernel_launch(void* const* d_in, const int* in_sizes, int n_in,
                              void* d_out, int out_size, void* d_ws,
                              size_t ws_size, hipStream_t stream) {
  const float* x      = (const float*)d_in[0];
  const float* w_in   = (const float*)d_in[1];
  const float* conv_w = (const float*)d_in[2];
  const float* conv_b = (const float*)d_in[3];
  const float* w_xp   = (const float*)d_in[4];
  const float* w_dt   = (const float*)d_in[5];
  const float* dt_b   = (const float*)d_in[6];
  const float* A_log  = (const float*)d_in[7];
  const float* Dv     = (const float*)d_in[8];
  const float* w_out  = (const float*)d_in[9];
  const float* rms_w  = (const float*)d_in[10];
  float* out = (float*)d_out;

  const int ML = BB * LL;  // 4096
  char* wsp = (char*)d_ws;
  size_t off = 0;
  auto alloc = [&](size_t bytes) -> void* {
    void* p = wsp + off;
    off += (bytes + 255) & ~(size_t)255;
    return p;
  };
  auto* xn_bf   = (__hip_bfloat16*)alloc((size_t)ML * DM * 2);
  auto* w_in_bf = (__hip_bfloat16*)alloc((size_t)2 * DI * DM * 2);
  auto* w_xp_bf = (__hip_bfloat16*)alloc((size_t)80 * DI * 2);
  auto* w_dt_bf = (__hip_bfloat16*)alloc((size_t)DI * 64 * 2);
  auto* w_out_bf= (__hip_bfloat16*)alloc((size_t)DM * DI * 2);
  auto* xz      = (float*)alloc((size_t)ML * 2 * DI * 4);
  auto* xs      = (float*)alloc((size_t)ML * DI * 4);
  auto* xs_bf   = (__hip_bfloat16*)alloc((size_t)ML * DI * 2);
  auto* dBC     = (float*)alloc((size_t)ML * 80 * 4);
  auto* dlt_in  = (__hip_bfloat16*)alloc((size_t)ML * 64 * 2);
  auto* delta   = (float*)alloc((size_t)ML * DI * 4);
  auto* carryA  = (float*)alloc((size_t)BB * NC * DS * DI * 4);
  auto* carryB  = (float*)alloc((size_t)BB * NC * DS * DI * 4);
  auto* hinit   = (float*)alloc((size_t)BB * NC * DS * DI * 4);
  auto* yg_bf   = (__hip_bfloat16*)alloc((size_t)ML * DI * 2);

  // 1. RMSNorm -> bf16
  rmsnorm_kernel<<<ML, 256, 0, stream>>>(x, rms_w, xn_bf);
  // 2. weight conversions
  cvt_bf16<<<(2 * DI * DM + 255) / 256, 256, 0, stream>>>(w_in, w_in_bf, 2 * DI * DM);
  cvt_bf16<<<(80 * DI + 255) / 256, 256, 0, stream>>>(w_xp, w_xp_bf, 80 * DI);
  cvt_bf16<<<(DM * DI + 255) / 256, 256, 0, stream>>>(w_out, w_out_bf, DM * DI);
  cvt_dtw<<<(DI * 64) / 256, 256, 0, stream>>>(w_dt, w_dt_bf);
  // 3. in_proj: xz = xn @ w_in^T   (M=4096,N=3072,K=768)
  gemm_bt<0><<<dim3((2 * DI) / 64, ML / 64), 256, 0, stream>>>(
      (const unsigned short*)xn_bf, (const unsigned short*)w_in_bf, xz,
      ML, 2 * DI, DM, nullptr);
  // 4. conv + silu
  conv_silu_kernel<<<(ML * DI) / 256, 256, 0, stream>>>(xz, conv_w, conv_b, xs, xs_bf);
  // 5. x_proj: dBC = xs @ w_xp^T  (M=4096,N=80,K=1536)
  gemm_bt<0><<<dim3(2, ML / 64), 256, 0, stream>>>(
      (const unsigned short*)xs_bf, (const unsigned short*)w_xp_bf, dBC,
      ML, 80, DI, nullptr);
  // 6. split delta part -> padded bf16
  split_dbc<<<(ML * 64) / 256, 256, 0, stream>>>(dBC, dlt_in);
  // 7. dt_proj + softplus: delta (M=4096,N=1536,K=64)
  gemm_bt<1><<<dim3(DI / 64, ML / 64), 256, 0, stream>>>(
      (const unsigned short*)dlt_in, (const unsigned short*)w_dt_bf, delta,
      ML, DI, 64, dt_b);
  // 8. chunked scan
  scan_passA<<<BB * NC * 6, 256, 0, stream>>>(delta, xs, dBC, A_log, carryA, carryB);
  scan_passB<<<(BB * DS * DI) / 256, 256, 0, stream>>>(carryA, carryB, hinit);
  scan_passC<<<BB * NC * 6, 256, 0, stream>>>(delta, xs, dBC, A_log, Dv, xz, hinit, yg_bf);
  // 9. out_proj + residual: out = yg @ w_out^T + x  (M=4096,N=768,K=1536)
  gemm_bt<2><<<dim3(DM / 64, ML / 64), 256, 0, stream>>>(
      (const unsigned short*)yg_bf, (const unsigned short*)w_out_bf, out,
      ML, DM, DI, x);
}

// Round 2
// 320.174 us; speedup vs baseline: 1.0369x; 1.0369x over previous
//
#include <hip/hip_runtime.h>
#include <hip/hip_bf16.h>

// Mamba block fwd, B=2 L=2048 DM=768 DI=1536 DS=16 DCONV=4 DTR=48
// Round 2: m97-style 128-tile GEMM with global_load_lds (width 16) for
// gemm1/gemm3/gemm4; split-K atomic GEMM for x_proj; fused weight cvt.

#define BB 2
#define LL 2048
#define DM 768
#define DI 1536
#define DS 16
#define DTR 48
#define NC 64
#define CL 32

typedef __attribute__((ext_vector_type(8))) __bf16 bf16x8;
typedef __attribute__((ext_vector_type(4))) float f32x4;

// ---------------- RMSNorm -> bf16 ----------------
__global__ __launch_bounds__(256) void rmsnorm_kernel(
    const float* __restrict__ x, const float* __restrict__ rmsw,
    __hip_bfloat16* __restrict__ xn) {
  const int row = blockIdx.x;
  const int tid = threadIdx.x;
  const float* xr = x + (size_t)row * DM;
  float v0 = xr[tid], v1 = xr[tid + 256], v2 = xr[tid + 512];
  float ss = v0 * v0 + v1 * v1 + v2 * v2;
  for (int off = 32; off; off >>= 1) ss += __shfl_down(ss, off);
  __shared__ float sred[4];
  __shared__ float sscale;
  if ((tid & 63) == 0) sred[tid >> 6] = ss;
  __syncthreads();
  if (tid == 0) {
    float s = sred[0] + sred[1] + sred[2] + sred[3];
    sscale = rsqrtf(s * (1.f / DM) + 1e-5f);
  }
  __syncthreads();
  float sc = sscale;
  __hip_bfloat16* o = xn + (size_t)row * DM;
  o[tid]       = __float2bfloat16(v0 * sc * rmsw[tid]);
  o[tid + 256] = __float2bfloat16(v1 * sc * rmsw[tid + 256]);
  o[tid + 512] = __float2bfloat16(v2 * sc * rmsw[tid + 512]);
}

// ---------------- fused weight conversions ----------------
__global__ __launch_bounds__(256) void cvt_weights(
    const float* __restrict__ w_in, const float* __restrict__ w_xp,
    const float* __restrict__ w_out, const float* __restrict__ w_dt,
    __hip_bfloat16* __restrict__ o_in, __hip_bfloat16* __restrict__ o_xp,
    __hip_bfloat16* __restrict__ o_out, __hip_bfloat16* __restrict__ o_dt) {
  int idx = blockIdx.x * 256 + threadIdx.x;
  const int n1 = 2 * DI * DM, n2 = 80 * DI, n3 = DM * DI, n4 = DI * 64;
  if (idx < n1) { o_in[idx] = __float2bfloat16(w_in[idx]); return; }
  idx -= n1;
  if (idx < n2) { o_xp[idx] = __float2bfloat16(w_xp[idx]); return; }
  idx -= n2;
  if (idx < n3) { o_out[idx] = __float2bfloat16(w_out[idx]); return; }
  idx -= n3;
  if (idx < n4) {
    int n = idx >> 6, k = idx & 63;
    o_dt[idx] = __float2bfloat16(k < DTR ? w_dt[n * DTR + k] : 0.f);
  }
}

// dBC delta part (4096,80 cols 0..47) -> (4096,64) zero-padded bf16
__global__ __launch_bounds__(256) void split_dbc(
    const float* __restrict__ dBC, __hip_bfloat16* __restrict__ din) {
  int idx = blockIdx.x * 256 + threadIdx.x;  // 4096*64
  int m = idx >> 6, k = idx & 63;
  float v = (k < DTR) ? dBC[(size_t)m * 80 + k] : 0.f;
  din[idx] = __float2bfloat16(v);
}

// ------------- m97-style GEMM: C[M,N]=A[M,K]*B[N,K]^T, 128xTN tile ---------
// EPI 0: none. EPI 1: softplus(acc+bias[n]). EPI 2: acc+res[m,n].
// All dims must divide tiles exactly (they do for our shapes).
template <int EPI, int TN>
__global__ __launch_bounds__(256) void gemm128(
    const unsigned short* __restrict__ A, const unsigned short* __restrict__ B,
    float* __restrict__ C, int M, int N, int K, const float* __restrict__ ep) {
  constexpr int WM = (TN == 128) ? 2 : 4;
  constexpr int MI = 128 / (WM * 16);   // 4 (TN=128) or 2 (TN=64)
  constexpr int NI = 4;
  constexpr int BCH = (TN * 64) / 4096; // B chunks: 2 or 1
  __shared__ __align__(16) unsigned short Al[128 * 32];
  __shared__ __align__(16) unsigned short Bl[TN * 32];
  const int tid = threadIdx.x;
  const int wave = tid >> 6, lane = tid & 63;
  const int wm = (TN == 128) ? (wave >> 1) : wave;
  const int wn = (TN == 128) ? (wave & 1) : 0;
  const int lr = lane & 15, q = lane >> 4;
  const int m0 = blockIdx.y * 128, n0 = blockIdx.x * TN;
  const char* Ab = (const char*)A;
  const char* Bb = (const char*)B;
  const size_t Kb = (size_t)K * 2;
  f32x4 acc[MI][NI] = {};
  for (int k0 = 0; k0 < K; k0 += 32) {
    __syncthreads();
#pragma unroll
    for (int c = 0; c < 2; ++c) {
      int lin = (c * 4 + wave) * 1024 + lane * 16;
      int row = lin >> 6, col = lin & 63;
      __builtin_amdgcn_global_load_lds(
          (const __attribute__((address_space(1))) unsigned int*)
              (Ab + (size_t)(m0 + row) * Kb + (size_t)k0 * 2 + col),
          (__attribute__((address_space(3))) unsigned int*)
              ((char*)Al + (c * 4 + wave) * 1024),
          16, 0, 0);
    }
#pragma unroll
    for (int c = 0; c < BCH; ++c) {
      int lin = (c * 4 + wave) * 1024 + lane * 16;
      int row = lin >> 6, col = lin & 63;
      __builtin_amdgcn_global_load_lds(
          (const __attribute__((address_space(1))) unsigned int*)
              (Bb + (size_t)(n0 + row) * Kb + (size_t)k0 * 2 + col),
          (__attribute__((address_space(3))) unsigned int*)
              ((char*)Bl + (c * 4 + wave) * 1024),
          16, 0, 0);
    }
    __syncthreads();
    bf16x8 af[MI], bfr[NI];
#pragma unroll
    for (int mi = 0; mi < MI; ++mi)
      af[mi] = *(const bf16x8*)(Al + (wm * (MI * 16) + mi * 16 + lr) * 32 + q * 8);
#pragma unroll
    for (int ni = 0; ni < NI; ++ni)
      bfr[ni] = *(const bf16x8*)(Bl + (wn * (NI * 16) + ni * 16 + lr) * 32 + q * 8);
#pragma unroll
    for (int mi = 0; mi < MI; ++mi)
#pragma unroll
      for (int ni = 0; ni < NI; ++ni)
        acc[mi][ni] = __builtin_amdgcn_mfma_f32_16x16x32_bf16(
            af[mi], bfr[ni], acc[mi][ni], 0, 0, 0);
  }
#pragma unroll
  for (int mi = 0; mi < MI; ++mi) {
#pragma unroll
    for (int ni = 0; ni < NI; ++ni) {
      int col = n0 + wn * (NI * 16) + ni * 16 + lr;
      int rowb = m0 + wm * (MI * 16) + mi * 16 + q * 4;
#pragma unroll
      for (int r = 0; r < 4; ++r) {
        float v = acc[mi][ni][r];
        size_t ci = (size_t)(rowb + r) * N + col;
        if (EPI == 1) {
          v += ep[col];
          v = fmaxf(v, 0.f) + log1pf(__expf(-fabsf(v)));
        } else if (EPI == 2) {
          v += ep[ci];
        }
        C[ci] = v;
      }
    }
  }
}

// ------- x_proj GEMM: 64x64 tile, split-K over blockIdx.z, atomic epi ------
__global__ __launch_bounds__(256) void gemm_xproj(
    const unsigned short* __restrict__ A, const unsigned short* __restrict__ B,
    float* __restrict__ C, int M, int N, int K, int klen) {
  __shared__ unsigned short Al[64 * 40];
  __shared__ unsigned short Bl[64 * 40];
  const int tid = threadIdx.x;
  const int m0 = blockIdx.y << 6, n0 = blockIdx.x << 6;
  const int kb = blockIdx.z * klen, ke = kb + klen;
  const int srow = tid >> 2, scg = tid & 3;
  const int wave = tid >> 6, lane = tid & 63;
  const int wm = wave >> 1, wn = wave & 1;
  const int lr = lane & 15, q = lane >> 4;
  f32x4 acc[2][2] = {};
  const size_t arow_off = (size_t)(m0 + srow) * K + scg * 8;
  const int brow = n0 + srow;
  const size_t brow_off = (size_t)brow * K + scg * 8;
  for (int k0 = kb; k0 < ke; k0 += 32) {
    int4 av = *(const int4*)(A + arow_off + k0);
    int4 bv = make_int4(0, 0, 0, 0);
    if (brow < N) bv = *(const int4*)(B + brow_off + k0);
    __syncthreads();
    *(int4*)(Al + srow * 40 + scg * 8) = av;
    *(int4*)(Bl + srow * 40 + scg * 8) = bv;
    __syncthreads();
    bf16x8 af[2], bfr[2];
#pragma unroll
    for (int mi = 0; mi < 2; ++mi)
      af[mi] = *(const bf16x8*)(Al + (wm * 32 + mi * 16 + lr) * 40 + q * 8);
#pragma unroll
    for (int ni = 0; ni < 2; ++ni)
      bfr[ni] = *(const bf16x8*)(Bl + (wn * 32 + ni * 16 + lr) * 40 + q * 8);
#pragma unroll
    for (int mi = 0; mi < 2; ++mi)
#pragma unroll
      for (int ni = 0; ni < 2; ++ni)
        acc[mi][ni] = __builtin_amdgcn_mfma_f32_16x16x32_bf16(
            af[mi], bfr[ni], acc[mi][ni], 0, 0, 0);
  }
#pragma unroll
  for (int mi = 0; mi < 2; ++mi) {
#pragma unroll
    for (int ni = 0; ni < 2; ++ni) {
      int nn = n0 + wn * 32 + ni * 16 + lr;
      if (nn >= N) continue;
      int mbase = m0 + wm * 32 + mi * 16 + q * 4;
#pragma unroll
      for (int r = 0; r < 4; ++r)
        atomicAdd(&C[(size_t)(mbase + r) * N + nn], acc[mi][ni][r]);
    }
  }
}

// ---------------- causal depthwise conv (k=4) + SiLU ----------------
__global__ __launch_bounds__(256) void conv_silu_kernel(
    const float* __restrict__ xz, const float* __restrict__ cw,
    const float* __restrict__ cb, float* __restrict__ xs,
    __hip_bfloat16* __restrict__ xsb) {
  int idx = blockIdx.x * 256 + threadIdx.x;  // BB*LL*DI
  int d = idx % DI;
  int bl = idx / DI;
  int l = bl & (LL - 1);
  float acc = cb[d];
#pragma unroll
  for (int j = 0; j < 4; ++j) {
    int ls = l - 3 + j;
    if (ls >= 0) acc += xz[(size_t)(bl - 3 + j) * (2 * DI) + d] * cw[d * 4 + j];
  }
  float s = acc * (1.f / (1.f + __expf(-acc)));
  xs[idx] = s;
  xsb[idx] = __float2bfloat16(s);
}

// ---------------- scan pass A: per-chunk carries ----------------
__global__ __launch_bounds__(256) void scan_passA(
    const float* __restrict__ delta, const float* __restrict__ xs,
    const float* __restrict__ dBC, const float* __restrict__ A_log,
    float* __restrict__ cA, float* __restrict__ cB) {
  __shared__ float Bs[CL * DS];
  const int bid = blockIdx.x;
  const int dg = bid % 6;
  const int chunk = (bid / 6) % NC;
  const int b = bid / (6 * NC);
  const int tid = threadIdx.x;
  const int d = dg * 256 + tid;
  const size_t bl0 = (size_t)b * LL + chunk * CL;
  for (int i = tid; i < CL * DS; i += 256) {
    int l = i >> 4, n = i & 15;
    Bs[i] = dBC[(bl0 + l) * 80 + DTR + n];
  }
  float Av[DS];
#pragma unroll
  for (int n = 0; n < DS; ++n) Av[n] = -__expf(A_log[d * DS + n]);
  float ap[DS], bc[DS];
#pragma unroll
  for (int n = 0; n < DS; ++n) { ap[n] = 1.f; bc[n] = 0.f; }
  __syncthreads();
  for (int t = 0; t < CL; ++t) {
    float dv = delta[(bl0 + t) * DI + d];
    float xv = xs[(bl0 + t) * DI + d];
    float dx = dv * xv;
#pragma unroll
    for (int n = 0; n < DS; ++n) {
      float a = __expf(dv * Av[n]) * 2.f - 1.f;
      bc[n] = a * bc[n] + dx * Bs[t * DS + n];
      ap[n] *= a;
    }
  }
  size_t base = ((size_t)(b * NC + chunk) * DS) * DI + d;
#pragma unroll
  for (int n = 0; n < DS; ++n) {
    cA[base + (size_t)n * DI] = ap[n];
    cB[base + (size_t)n * DI] = bc[n];
  }
}

// ---------------- scan pass B: scan over chunk aggregates ----------------
__global__ __launch_bounds__(256) void scan_passB(
    const float* __restrict__ cA, const float* __restrict__ cB,
    float* __restrict__ hinit) {
  int idx = blockIdx.x * 256 + threadIdx.x;  // BB*DS*DI
  int d = idx % DI;
  int n = (idx / DI) % DS;
  int b = idx / (DI * DS);
  float h = 0.f;
  for (int c = 0; c < NC; ++c) {
    size_t base = ((size_t)(b * NC + c) * DS + n) * DI + d;
    hinit[base] = h;
    h = cA[base] * h + cB[base];
  }
}

// ---------------- scan pass C: replay + C-reduce + D*xs + silu(z) gate -----
__global__ __launch_bounds__(256) void scan_passC(
    const float* __restrict__ delta, const float* __restrict__ xs,
    const float* __restrict__ dBC, const float* __restrict__ A_log,
    const float* __restrict__ Dv, const float* __restrict__ xz,
    const float* __restrict__ hinit, __hip_bfloat16* __restrict__ yg) {
  __shared__ float Bs[CL * DS];
  __shared__ float Cs[CL * DS];
  const int bid = blockIdx.x;
  const int dg = bid % 6;
  const int chunk = (bid / 6) % NC;
  const int b = bid / (6 * NC);
  const int tid = threadIdx.x;
  const int d = dg * 256 + tid;
  const size_t bl0 = (size_t)b * LL + chunk * CL;
  for (int i = tid; i < CL * DS; i += 256) {
    int l = i >> 4, n = i & 15;
    Bs[i] = dBC[(bl0 + l) * 80 + DTR + n];
    Cs[i] = dBC[(bl0 + l) * 80 + DTR + DS + n];
  }
  float Av[DS];
#pragma unroll
  for (int n = 0; n < DS; ++n) Av[n] = -__expf(A_log[d * DS + n]);
  float h[DS];
  size_t hbase = ((size_t)(b * NC + chunk) * DS) * DI + d;
#pragma unroll
  for (int n = 0; n < DS; ++n) h[n] = hinit[hbase + (size_t)n * DI];
  float Dd = Dv[d];
  __syncthreads();
  for (int t = 0; t < CL; ++t) {
    float dv = delta[(bl0 + t) * DI + d];
    float xv = xs[(bl0 + t) * DI + d];
    float zv = xz[(bl0 + t) * (2 * DI) + DI + d];
    float dx = dv * xv;
    float y = 0.f;
#pragma unroll
    for (int n = 0; n < DS; ++n) {
      float a = __expf(dv * Av[n]) * 2.f - 1.f;
      h[n] = a * h[n] + dx * Bs[t * DS + n];
      y += h[n] * Cs[t * DS + n];
    }
    y += Dd * xv;
    float g = zv / (1.f + __expf(-zv));
    yg[(bl0 + t) * DI + d] = __float2bfloat16(y * g);
  }
}

// ---------------- host launch ----------------
extern "C" void kernel_launch(void* const* d_in, const int* in_sizes, int n_in,
                              void* d_out, int out_size, void* d_ws,
                              size_t ws_size, hipStream_t stream) {
  const float* x      = (const float*)d_in[0];
  const float* w_in   = (const float*)d_in[1];
  const float* conv_w = (const float*)d_in[2];
  const float* conv_b = (const float*)d_in[3];
  const float* w_xp   = (const float*)d_in[4];
  const float* w_dt   = (const float*)d_in[5];
  const float* dt_b   = (const float*)d_in[6];
  const float* A_log  = (const float*)d_in[7];
  const float* Dv     = (const float*)d_in[8];
  const float* w_out  = (const float*)d_in[9];
  const float* rms_w  = (const float*)d_in[10];
  float* out = (float*)d_out;

  const int ML = BB * LL;  // 4096
  char* wsp = (char*)d_ws;
  size_t off = 0;
  auto alloc = [&](size_t bytes) -> void* {
    void* p = wsp + off;
    off += (bytes + 255) & ~(size_t)255;
    return p;
  };
  auto* xn_bf   = (__hip_bfloat16*)alloc((size_t)ML * DM * 2);
  auto* w_in_bf = (__hip_bfloat16*)alloc((size_t)2 * DI * DM * 2);
  auto* w_xp_bf = (__hip_bfloat16*)alloc((size_t)80 * DI * 2);
  auto* w_dt_bf = (__hip_bfloat16*)alloc((size_t)DI * 64 * 2);
  auto* w_out_bf= (__hip_bfloat16*)alloc((size_t)DM * DI * 2);
  auto* xz      = (float*)alloc((size_t)ML * 2 * DI * 4);
  auto* xs      = (float*)alloc((size_t)ML * DI * 4);
  auto* xs_bf   = (__hip_bfloat16*)alloc((size_t)ML * DI * 2);
  auto* dBC     = (float*)alloc((size_t)ML * 80 * 4);
  auto* dlt_in  = (__hip_bfloat16*)alloc((size_t)ML * 64 * 2);
  auto* delta   = (float*)alloc((size_t)ML * DI * 4);
  auto* carryA  = (float*)alloc((size_t)BB * NC * DS * DI * 4);
  auto* carryB  = (float*)alloc((size_t)BB * NC * DS * DI * 4);
  auto* hinit   = (float*)alloc((size_t)BB * NC * DS * DI * 4);
  auto* yg_bf   = (__hip_bfloat16*)alloc((size_t)ML * DI * 2);

  // 1. RMSNorm -> bf16
  rmsnorm_kernel<<<ML, 256, 0, stream>>>(x, rms_w, xn_bf);
  // 2. fused weight conversions (3760128 elements)
  cvt_weights<<<(2 * DI * DM + 80 * DI + DM * DI + DI * 64 + 255) / 256, 256, 0,
                stream>>>(w_in, w_xp, w_out, w_dt, w_in_bf, w_xp_bf, w_out_bf,
                          w_dt_bf);
  // 3. in_proj: xz = xn @ w_in^T   (M=4096,N=3072,K=768)
  gemm128<0, 128><<<dim3(3072 / 128, ML / 128), 256, 0, stream>>>(
      (const unsigned short*)xn_bf, (const unsigned short*)w_in_bf, xz,
      ML, 2 * DI, DM, nullptr);
  // 4. conv + silu
  conv_silu_kernel<<<(ML * DI) / 256, 256, 0, stream>>>(xz, conv_w, conv_b, xs, xs_bf);
  // 5. x_proj: dBC = xs @ w_xp^T  (M=4096,N=80,K=1536), split-K=6 + atomics
  hipMemsetAsync(dBC, 0, (size_t)ML * 80 * 4, stream);
  gemm_xproj<<<dim3(2, ML / 64, 6), 256, 0, stream>>>(
      (const unsigned short*)xs_bf, (const unsigned short*)w_xp_bf, dBC,
      ML, 80, DI, DI / 6);
  // 6. split delta part -> padded bf16
  split_dbc<<<(ML * 64) / 256, 256, 0, stream>>>(dBC, dlt_in);
  // 7. dt_proj + softplus: delta (M=4096,N=1536,K=64)
  gemm128<1, 128><<<dim3(DI / 128, ML / 128), 256, 0, stream>>>(
      (const unsigned short*)dlt_in, (const unsigned short*)w_dt_bf, delta,
      ML, DI, 64, dt_b);
  // 8. chunked scan
  scan_passA<<<BB * NC * 6, 256, 0, stream>>>(delta, xs, dBC, A_log, carryA, carryB);
  scan_passB<<<(BB * DS * DI) / 256, 256, 0, stream>>>(carryA, carryB, hinit);
  scan_passC<<<BB * NC * 6, 256, 0, stream>>>(delta, xs, dBC, A_log, Dv, xz, hinit, yg_bf);
  // 9. out_proj + residual: out = yg @ w_out^T + x  (M=4096,N=768,K=1536)
  gemm128<2, 64><<<dim3(DM / 64, ML / 128), 256, 0, stream>>>(
      (const unsigned short*)yg_bf, (const unsigned short*)w_out_bf, out,
      ML, DM, DI, x);
}

// Round 3
// 318.528 us; speedup vs baseline: 1.0422x; 1.0052x over previous
//
#include <hip/hip_runtime.h>
#include <hip/hip_bf16.h>

// Mamba block fwd, B=2 L=2048 DM=768 DI=1536 DS=16 DCONV=4 DTR=48
// Round 3: gemm128 epilogue rewritten as LDS-transpose -> float4 coalesced
// stores (round-2 scattered dword epilogue was latency-bound at 1.5 blk/CU).

#define BB 2
#define LL 2048
#define DM 768
#define DI 1536
#define DS 16
#define DTR 48
#define NC 64
#define CL 32

typedef __attribute__((ext_vector_type(8))) __bf16 bf16x8;
typedef __attribute__((ext_vector_type(4))) float f32x4;

// ---------------- RMSNorm -> bf16 ----------------
__global__ __launch_bounds__(256) void rmsnorm_kernel(
    const float* __restrict__ x, const float* __restrict__ rmsw,
    __hip_bfloat16* __restrict__ xn) {
  const int row = blockIdx.x;
  const int tid = threadIdx.x;
  const float* xr = x + (size_t)row * DM;
  float v0 = xr[tid], v1 = xr[tid + 256], v2 = xr[tid + 512];
  float ss = v0 * v0 + v1 * v1 + v2 * v2;
  for (int off = 32; off; off >>= 1) ss += __shfl_down(ss, off);
  __shared__ float sred[4];
  __shared__ float sscale;
  if ((tid & 63) == 0) sred[tid >> 6] = ss;
  __syncthreads();
  if (tid == 0) {
    float s = sred[0] + sred[1] + sred[2] + sred[3];
    sscale = rsqrtf(s * (1.f / DM) + 1e-5f);
  }
  __syncthreads();
  float sc = sscale;
  __hip_bfloat16* o = xn + (size_t)row * DM;
  o[tid]       = __float2bfloat16(v0 * sc * rmsw[tid]);
  o[tid + 256] = __float2bfloat16(v1 * sc * rmsw[tid + 256]);
  o[tid + 512] = __float2bfloat16(v2 * sc * rmsw[tid + 512]);
}

// ---------------- fused weight conversions ----------------
__global__ __launch_bounds__(256) void cvt_weights(
    const float* __restrict__ w_in, const float* __restrict__ w_xp,
    const float* __restrict__ w_out, const float* __restrict__ w_dt,
    __hip_bfloat16* __restrict__ o_in, __hip_bfloat16* __restrict__ o_xp,
    __hip_bfloat16* __restrict__ o_out, __hip_bfloat16* __restrict__ o_dt) {
  int idx = blockIdx.x * 256 + threadIdx.x;
  const int n1 = 2 * DI * DM, n2 = 80 * DI, n3 = DM * DI, n4 = DI * 64;
  if (idx < n1) { o_in[idx] = __float2bfloat16(w_in[idx]); return; }
  idx -= n1;
  if (idx < n2) { o_xp[idx] = __float2bfloat16(w_xp[idx]); return; }
  idx -= n2;
  if (idx < n3) { o_out[idx] = __float2bfloat16(w_out[idx]); return; }
  idx -= n3;
  if (idx < n4) {
    int n = idx >> 6, k = idx & 63;
    o_dt[idx] = __float2bfloat16(k < DTR ? w_dt[n * DTR + k] : 0.f);
  }
}

// dBC delta part (4096,80 cols 0..47) -> (4096,64) zero-padded bf16
__global__ __launch_bounds__(256) void split_dbc(
    const float* __restrict__ dBC, __hip_bfloat16* __restrict__ din) {
  int idx = blockIdx.x * 256 + threadIdx.x;  // 4096*64
  int m = idx >> 6, k = idx & 63;
  float v = (k < DTR) ? dBC[(size_t)m * 80 + k] : 0.f;
  din[idx] = __float2bfloat16(v);
}

// ------------- m97-style GEMM: C[M,N]=A[M,K]*B[N,K]^T, 128xTN tile ---------
// EPI 0: none. EPI 1: softplus(acc+bias[n]). EPI 2: acc+res[m,n].
// Epilogue: LDS transpose -> float4 coalesced stores.
template <int EPI, int TN>
__global__ __launch_bounds__(256) void gemm128(
    const unsigned short* __restrict__ A, const unsigned short* __restrict__ B,
    float* __restrict__ C, int M, int N, int K, const float* __restrict__ ep) {
  constexpr int WM = (TN == 128) ? 2 : 4;
  constexpr int MI = 128 / (WM * 16);   // 4 (TN=128) or 2 (TN=64)
  constexpr int NI = 4;
  constexpr int BCH = (TN * 64) / 4096; // B chunks: 2 or 1
  constexpr int CROWS = (TN == 128) ? 32 : 64;  // epilogue chunk rows
  constexpr int CSTR = TN + 4;                  // padded float stride
  constexpr int STG = 8192 + TN * 64;           // staging bytes
  constexpr int CLB = CROWS * CSTR * 4;         // epilogue bytes
  constexpr int SMEMB = STG > CLB ? STG : CLB;
  __shared__ __align__(16) char smem[SMEMB];
  unsigned short* Al = (unsigned short*)smem;
  unsigned short* Bl = (unsigned short*)(smem + 8192);
  float* Cl = (float*)smem;
  const int tid = threadIdx.x;
  const int wave = tid >> 6, lane = tid & 63;
  const int wm = (TN == 128) ? (wave >> 1) : wave;
  const int wn = (TN == 128) ? (wave & 1) : 0;
  const int lr = lane & 15, q = lane >> 4;
  const int m0 = blockIdx.y * 128, n0 = blockIdx.x * TN;
  const char* Ab = (const char*)A;
  const char* Bb = (const char*)B;
  const size_t Kb = (size_t)K * 2;
  f32x4 acc[MI][NI] = {};
  for (int k0 = 0; k0 < K; k0 += 32) {
    __syncthreads();
#pragma unroll
    for (int c = 0; c < 2; ++c) {
      int lin = (c * 4 + wave) * 1024 + lane * 16;
      int row = lin >> 6, col = lin & 63;
      __builtin_amdgcn_global_load_lds(
          (const __attribute__((address_space(1))) unsigned int*)
              (Ab + (size_t)(m0 + row) * Kb + (size_t)k0 * 2 + col),
          (__attribute__((address_space(3))) unsigned int*)
              ((char*)Al + (c * 4 + wave) * 1024),
          16, 0, 0);
    }
#pragma unroll
    for (int c = 0; c < BCH; ++c) {
      int lin = (c * 4 + wave) * 1024 + lane * 16;
      int row = lin >> 6, col = lin & 63;
      __builtin_amdgcn_global_load_lds(
          (const __attribute__((address_space(1))) unsigned int*)
              (Bb + (size_t)(n0 + row) * Kb + (size_t)k0 * 2 + col),
          (__attribute__((address_space(3))) unsigned int*)
              ((char*)Bl + (c * 4 + wave) * 1024),
          16, 0, 0);
    }
    __syncthreads();
    bf16x8 af[MI], bfr[NI];
#pragma unroll
    for (int mi = 0; mi < MI; ++mi)
      af[mi] = *(const bf16x8*)(Al + (wm * (MI * 16) + mi * 16 + lr) * 32 + q * 8);
#pragma unroll
    for (int ni = 0; ni < NI; ++ni)
      bfr[ni] = *(const bf16x8*)(Bl + (wn * (NI * 16) + ni * 16 + lr) * 32 + q * 8);
#pragma unroll
    for (int mi = 0; mi < MI; ++mi)
#pragma unroll
      for (int ni = 0; ni < NI; ++ni)
        acc[mi][ni] = __builtin_amdgcn_mfma_f32_16x16x32_bf16(
            af[mi], bfr[ni], acc[mi][ni], 0, 0, 0);
  }
  // ---- epilogue: per-mi LDS transpose + coalesced float4 stores ----
#pragma unroll
  for (int mi = 0; mi < MI; ++mi) {
    __syncthreads();
    const int rloc = wm * 16 + q * 4;
#pragma unroll
    for (int ni = 0; ni < NI; ++ni) {
      int col = wn * (NI * 16) + ni * 16 + lr;
#pragma unroll
      for (int r = 0; r < 4; ++r)
        Cl[(rloc + r) * CSTR + col] = acc[mi][ni][r];
    }
    __syncthreads();
#pragma unroll
    for (int j = 0; j < 4; ++j) {
      int rl, c4;
      if (TN == 128) { rl = (tid >> 5) + j * 8;  c4 = tid & 31; }
      else           { rl = (tid >> 4) + j * 16; c4 = tid & 15; }
      float4 v = *(const float4*)&Cl[rl * CSTR + c4 * 4];
      int gcol = n0 + c4 * 4;
      int grow;
      if (TN == 128) grow = m0 + (rl >> 4) * 64 + mi * 16 + (rl & 15);
      else           grow = m0 + (rl >> 4) * 32 + mi * 16 + (rl & 15);
      size_t ci = (size_t)grow * N + gcol;
      if (EPI == 1) {
        float4 bb = *(const float4*)&ep[gcol];
        v.x += bb.x; v.y += bb.y; v.z += bb.z; v.w += bb.w;
        v.x = fmaxf(v.x, 0.f) + log1pf(__expf(-fabsf(v.x)));
        v.y = fmaxf(v.y, 0.f) + log1pf(__expf(-fabsf(v.y)));
        v.z = fmaxf(v.z, 0.f) + log1pf(__expf(-fabsf(v.z)));
        v.w = fmaxf(v.w, 0.f) + log1pf(__expf(-fabsf(v.w)));
      } else if (EPI == 2) {
        float4 rv = *(const float4*)&ep[ci];
        v.x += rv.x; v.y += rv.y; v.z += rv.z; v.w += rv.w;
      }
      *(float4*)&C[ci] = v;
    }
  }
}

// ------- x_proj GEMM: 64x64 tile, split-K over blockIdx.z, atomic epi ------
__global__ __launch_bounds__(256) void gemm_xproj(
    const unsigned short* __restrict__ A, const unsigned short* __restrict__ B,
    float* __restrict__ C, int M, int N, int K, int klen) {
  __shared__ unsigned short Al[64 * 40];
  __shared__ unsigned short Bl[64 * 40];
  const int tid = threadIdx.x;
  const int m0 = blockIdx.y << 6, n0 = blockIdx.x << 6;
  const int kb = blockIdx.z * klen, ke = kb + klen;
  const int srow = tid >> 2, scg = tid & 3;
  const int wave = tid >> 6, lane = tid & 63;
  const int wm = wave >> 1, wn = wave & 1;
  const int lr = lane & 15, q = lane >> 4;
  f32x4 acc[2][2] = {};
  const size_t arow_off = (size_t)(m0 + srow) * K + scg * 8;
  const int brow = n0 + srow;
  const size_t brow_off = (size_t)brow * K + scg * 8;
  for (int k0 = kb; k0 < ke; k0 += 32) {
    int4 av = *(const int4*)(A + arow_off + k0);
    int4 bv = make_int4(0, 0, 0, 0);
    if (brow < N) bv = *(const int4*)(B + brow_off + k0);
    __syncthreads();
    *(int4*)(Al + srow * 40 + scg * 8) = av;
    *(int4*)(Bl + srow * 40 + scg * 8) = bv;
    __syncthreads();
    bf16x8 af[2], bfr[2];
#pragma unroll
    for (int mi = 0; mi < 2; ++mi)
      af[mi] = *(const bf16x8*)(Al + (wm * 32 + mi * 16 + lr) * 40 + q * 8);
#pragma unroll
    for (int ni = 0; ni < 2; ++ni)
      bfr[ni] = *(const bf16x8*)(Bl + (wn * 32 + ni * 16 + lr) * 40 + q * 8);
#pragma unroll
    for (int mi = 0; mi < 2; ++mi)
#pragma unroll
      for (int ni = 0; ni < 2; ++ni)
        acc[mi][ni] = __builtin_amdgcn_mfma_f32_16x16x32_bf16(
            af[mi], bfr[ni], acc[mi][ni], 0, 0, 0);
  }
#pragma unroll
  for (int mi = 0; mi < 2; ++mi) {
#pragma unroll
    for (int ni = 0; ni < 2; ++ni) {
      int nn = n0 + wn * 32 + ni * 16 + lr;
      if (nn >= N) continue;
      int mbase = m0 + wm * 32 + mi * 16 + q * 4;
#pragma unroll
      for (int r = 0; r < 4; ++r)
        atomicAdd(&C[(size_t)(mbase + r) * N + nn], acc[mi][ni][r]);
    }
  }
}

// ---------------- causal depthwise conv (k=4) + SiLU ----------------
__global__ __launch_bounds__(256) void conv_silu_kernel(
    const float* __restrict__ xz, const float* __restrict__ cw,
    const float* __restrict__ cb, float* __restrict__ xs,
    __hip_bfloat16* __restrict__ xsb) {
  int idx = blockIdx.x * 256 + threadIdx.x;  // BB*LL*DI
  int d = idx % DI;
  int bl = idx / DI;
  int l = bl & (LL - 1);
  float acc = cb[d];
#pragma unroll
  for (int j = 0; j < 4; ++j) {
    int ls = l - 3 + j;
    if (ls >= 0) acc += xz[(size_t)(bl - 3 + j) * (2 * DI) + d] * cw[d * 4 + j];
  }
  float s = acc * (1.f / (1.f + __expf(-acc)));
  xs[idx] = s;
  xsb[idx] = __float2bfloat16(s);
}

// ---------------- scan pass A: per-chunk carries ----------------
__global__ __launch_bounds__(256) void scan_passA(
    const float* __restrict__ delta, const float* __restrict__ xs,
    const float* __restrict__ dBC, const float* __restrict__ A_log,
    float* __restrict__ cA, float* __restrict__ cB) {
  __shared__ float Bs[CL * DS];
  const int bid = blockIdx.x;
  const int dg = bid % 6;
  const int chunk = (bid / 6) % NC;
  const int b = bid / (6 * NC);
  const int tid = threadIdx.x;
  const int d = dg * 256 + tid;
  const size_t bl0 = (size_t)b * LL + chunk * CL;
  for (int i = tid; i < CL * DS; i += 256) {
    int l = i >> 4, n = i & 15;
    Bs[i] = dBC[(bl0 + l) * 80 + DTR + n];
  }
  float Av[DS];
#pragma unroll
  for (int n = 0; n < DS; ++n) Av[n] = -__expf(A_log[d * DS + n]);
  float ap[DS], bc[DS];
#pragma unroll
  for (int n = 0; n < DS; ++n) { ap[n] = 1.f; bc[n] = 0.f; }
  __syncthreads();
  for (int t = 0; t < CL; ++t) {
    float dv = delta[(bl0 + t) * DI + d];
    float xv = xs[(bl0 + t) * DI + d];
    float dx = dv * xv;
#pragma unroll
    for (int n = 0; n < DS; ++n) {
      float a = __expf(dv * Av[n]) * 2.f - 1.f;
      bc[n] = a * bc[n] + dx * Bs[t * DS + n];
      ap[n] *= a;
    }
  }
  size_t base = ((size_t)(b * NC + chunk) * DS) * DI + d;
#pragma unroll
  for (int n = 0; n < DS; ++n) {
    cA[base + (size_t)n * DI] = ap[n];
    cB[base + (size_t)n * DI] = bc[n];
  }
}

// ---------------- scan pass B: scan over chunk aggregates ----------------
__global__ __launch_bounds__(256) void scan_passB(
    const float* __restrict__ cA, const float* __restrict__ cB,
    float* __restrict__ hinit) {
  int idx = blockIdx.x * 256 + threadIdx.x;  // BB*DS*DI
  int d = idx % DI;
  int n = (idx / DI) % DS;
  int b = idx / (DI * DS);
  float h = 0.f;
  for (int c = 0; c < NC; ++c) {
    size_t base = ((size_t)(b * NC + c) * DS + n) * DI + d;
    hinit[base] = h;
    h = cA[base] * h + cB[base];
  }
}

// ---------------- scan pass C: replay + C-reduce + D*xs + silu(z) gate -----
__global__ __launch_bounds__(256) void scan_passC(
    const float* __restrict__ delta, const float* __restrict__ xs,
    const float* __restrict__ dBC, const float* __restrict__ A_log,
    const float* __restrict__ Dv, const float* __restrict__ xz,
    const float* __restrict__ hinit, __hip_bfloat16* __restrict__ yg) {
  __shared__ float Bs[CL * DS];
  __shared__ float Cs[CL * DS];
  const int bid = blockIdx.x;
  const int dg = bid % 6;
  const int chunk = (bid / 6) % NC;
  const int b = bid / (6 * NC);
  const int tid = threadIdx.x;
  const int d = dg * 256 + tid;
  const size_t bl0 = (size_t)b * LL + chunk * CL;
  for (int i = tid; i < CL * DS; i += 256) {
    int l = i >> 4, n = i & 15;
    Bs[i] = dBC[(bl0 + l) * 80 + DTR + n];
    Cs[i] = dBC[(bl0 + l) * 80 + DTR + DS + n];
  }
  float Av[DS];
#pragma unroll
  for (int n = 0; n < DS; ++n) Av[n] = -__expf(A_log[d * DS + n]);
  float h[DS];
  size_t hbase = ((size_t)(b * NC + chunk) * DS) * DI + d;
#pragma unroll
  for (int n = 0; n < DS; ++n) h[n] = hinit[hbase + (size_t)n * DI];
  float Dd = Dv[d];
  __syncthreads();
  for (int t = 0; t < CL; ++t) {
    float dv = delta[(bl0 + t) * DI + d];
    float xv = xs[(bl0 + t) * DI + d];
    float zv = xz[(bl0 + t) * (2 * DI) + DI + d];
    float dx = dv * xv;
    float y = 0.f;
#pragma unroll
    for (int n = 0; n < DS; ++n) {
      float a = __expf(dv * Av[n]) * 2.f - 1.f;
      h[n] = a * h[n] + dx * Bs[t * DS + n];
      y += h[n] * Cs[t * DS + n];
    }
    y += Dd * xv;
    float g = zv / (1.f + __expf(-zv));
    yg[(bl0 + t) * DI + d] = __float2bfloat16(y * g);
  }
}

// ---------------- host launch ----------------
extern "C" void kernel_launch(void* const* d_in, const int* in_sizes, int n_in,
                              void* d_out, int out_size, void* d_ws,
                              size_t ws_size, hipStream_t stream) {
  const float* x      = (const float*)d_in[0];
  const float* w_in   = (const float*)d_in[1];
  const float* conv_w = (const float*)d_in[2];
  const float* conv_b = (const float*)d_in[3];
  const float* w_xp   = (const float*)d_in[4];
  const float* w_dt   = (const float*)d_in[5];
  const float* dt_b   = (const float*)d_in[6];
  const float* A_log  = (const float*)d_in[7];
  const float* Dv     = (const float*)d_in[8];
  const float* w_out  = (const float*)d_in[9];
  const float* rms_w  = (const float*)d_in[10];
  float* out = (float*)d_out;

  const int ML = BB * LL;  // 4096
  char* wsp = (char*)d_ws;
  size_t off = 0;
  auto alloc = [&](size_t bytes) -> void* {
    void* p = wsp + off;
    off += (bytes + 255) & ~(size_t)255;
    return p;
  };
  auto* xn_bf   = (__hip_bfloat16*)alloc((size_t)ML * DM * 2);
  auto* w_in_bf = (__hip_bfloat16*)alloc((size_t)2 * DI * DM * 2);
  auto* w_xp_bf = (__hip_bfloat16*)alloc((size_t)80 * DI * 2);
  auto* w_dt_bf = (__hip_bfloat16*)alloc((size_t)DI * 64 * 2);
  auto* w_out_bf= (__hip_bfloat16*)alloc((size_t)DM * DI * 2);
  auto* xz      = (float*)alloc((size_t)ML * 2 * DI * 4);
  auto* xs      = (float*)alloc((size_t)ML * DI * 4);
  auto* xs_bf   = (__hip_bfloat16*)alloc((size_t)ML * DI * 2);
  auto* dBC     = (float*)alloc((size_t)ML * 80 * 4);
  auto* dlt_in  = (__hip_bfloat16*)alloc((size_t)ML * 64 * 2);
  auto* delta   = (float*)alloc((size_t)ML * DI * 4);
  auto* carryA  = (float*)alloc((size_t)BB * NC * DS * DI * 4);
  auto* carryB  = (float*)alloc((size_t)BB * NC * DS * DI * 4);
  auto* hinit   = (float*)alloc((size_t)BB * NC * DS * DI * 4);
  auto* yg_bf   = (__hip_bfloat16*)alloc((size_t)ML * DI * 2);

  // 1. RMSNorm -> bf16
  rmsnorm_kernel<<<ML, 256, 0, stream>>>(x, rms_w, xn_bf);
  // 2. fused weight conversions
  cvt_weights<<<(2 * DI * DM + 80 * DI + DM * DI + DI * 64 + 255) / 256, 256, 0,
                stream>>>(w_in, w_xp, w_out, w_dt, w_in_bf, w_xp_bf, w_out_bf,
                          w_dt_bf);
  // 3. in_proj: xz = xn @ w_in^T   (M=4096,N=3072,K=768)
  gemm128<0, 128><<<dim3(3072 / 128, ML / 128), 256, 0, stream>>>(
      (const unsigned short*)xn_bf, (const unsigned short*)w_in_bf, xz,
      ML, 2 * DI, DM, nullptr);
  // 4. conv + silu
  conv_silu_kernel<<<(ML * DI) / 256, 256, 0, stream>>>(xz, conv_w, conv_b, xs, xs_bf);
  // 5. x_proj: dBC = xs @ w_xp^T  (M=4096,N=80,K=1536), split-K=6 + atomics
  hipMemsetAsync(dBC, 0, (size_t)ML * 80 * 4, stream);
  gemm_xproj<<<dim3(2, ML / 64, 6), 256, 0, stream>>>(
      (const unsigned short*)xs_bf, (const unsigned short*)w_xp_bf, dBC,
      ML, 80, DI, DI / 6);
  // 6. split delta part -> padded bf16
  split_dbc<<<(ML * 64) / 256, 256, 0, stream>>>(dBC, dlt_in);
  // 7. dt_proj + softplus: delta (M=4096,N=1536,K=64)
  gemm128<1, 128><<<dim3(DI / 128, ML / 128), 256, 0, stream>>>(
      (const unsigned short*)dlt_in, (const unsigned short*)w_dt_bf, delta,
      ML, DI, 64, dt_b);
  // 8. chunked scan
  scan_passA<<<BB * NC * 6, 256, 0, stream>>>(delta, xs, dBC, A_log, carryA, carryB);
  scan_passB<<<(BB * DS * DI) / 256, 256, 0, stream>>>(carryA, carryB, hinit);
  scan_passC<<<BB * NC * 6, 256, 0, stream>>>(delta, xs, dBC, A_log, Dv, xz, hinit, yg_bf);
  // 9. out_proj + residual: out = yg @ w_out^T + x  (M=4096,N=768,K=1536)
  gemm128<2, 64><<<dim3(DM / 64, ML / 128), 256, 0, stream>>>(
      (const unsigned short*)yg_bf, (const unsigned short*)w_out_bf, out,
      ML, DM, DI, x);
}